// Round 20
// baseline (6590.665 us; speedup 1.0000x reference)
//
#include <hip/hip_runtime.h>
#include <math.h>

// RNN with short-term plasticity: persistent cooperative kernel,
// 8 groups of 32 WGs; each WG software-pipelines TWO batch-contexts.
//
// Round 20: r19's two-context structure made into a REAL pipeline.
// r19 failed because (a) the staged load was consumed immediately after
// issue (atile write waits on it) and (b) __syncthreads drains vmcnt(0),
// killing any in-flight prefetch at every barrier. Fixes:
//  - raw `s_waitcnt lgkmcnt(0)` + s_barrier (+ sched_barrier, rule #18)
//    instead of __syncthreads in the hot loop -> LDS-only drains; global
//    prefetch loads stay in flight across barriers.
//  - prefetch distance one full phase: phase C consumes atile[C] (written
//    last phase from regs issued the phase before), writes atile[C^1]
//    from in-flight regs, and issues its OWN ctx's next-step loads at
//    phase end (poll targets stamps set mid-phase, ~0.3-0.5us earlier).
//  - early stamp: ALL protocol stores (A publish + ZP partials) come from
//    wave 0 (owners tid<64), so wave 0 does s_waitcnt vmcnt(0) itself and
//    stamps mid-phase -- no block-wide pre-stamp drain.
// Protocol invariant unchanged from r11/r19: stamp(C)=t+2 certifies
// "read A(C,t) and published A(C,t+1)"; readers poll >= t+1 before
// loading A(C,t); poll -> s_barrier -> load gates every loader.
//
#define NH 1024
#define NB 32
#define NI 8
#define NO 8
#define TSTEPS 1000

#define NWG 256
#define BLK 512
#define NG 8          // groups (4 batches each)
#define NM 32         // members per group
#define GB 2          // batches per context
#define NCTX 2

#define OFF_Z 0
#define OFF_H (NB * TSTEPS * NO)            // 256000
#define OFF_R (OFF_H + NB * TSTEPS * NH)    // 33024000
#define OFF_U (OFF_R + NB * TSTEPS * NH)    // 65792000

#define A_PAR  (NG * NH * GB)               // 16384 floats (one parity)
#define A_CSZ  (2 * A_PAR)
#define ZP_PAR (NG * GB * NO * NM)          // 4096
#define ZP_CSZ (2 * ZP_PAR)
// ws: slots[2][NWG] 128B lines (64KB) -> then A[ctx], then ZP[ctx]
#define WS_A   (NCTX * NWG * 32)
#define WS_ZP  (WS_A + NCTX * A_CSZ)

#define ATS (NH + NM)   // atile stride (float2), padded row j -> j + (j>>5)

typedef unsigned long long u64;
typedef unsigned int u32;

__device__ __forceinline__ float2 aload2(const float* p) {
    u64 v = __hip_atomic_load((const u64*)p, __ATOMIC_RELAXED,
                              __HIP_MEMORY_SCOPE_AGENT);
    return __builtin_bit_cast(float2, v);
}
__device__ __forceinline__ float aload1(const float* p) {
    return __hip_atomic_load(p, __ATOMIC_RELAXED, __HIP_MEMORY_SCOPE_AGENT);
}
__device__ __forceinline__ void astore(float* p, float v) {
    __hip_atomic_store(p, v, __ATOMIC_RELAXED, __HIP_MEMORY_SCOPE_AGENT);
}
__device__ __forceinline__ u32 aload_u32(const u32* p) {
    return __hip_atomic_load(p, __ATOMIC_RELAXED, __HIP_MEMORY_SCOPE_AGENT);
}
__device__ __forceinline__ void astore_u32(u32* p, u32 v) {
    __hip_atomic_store(p, v, __ATOMIC_RELAXED, __HIP_MEMORY_SCOPE_AGENT);
}

// LDS-only barrier: drains ds ops, leaves global loads in flight.
__device__ __forceinline__ void bar_lgkm() {
    asm volatile("s_waitcnt lgkmcnt(0)" ::: "memory");
    __builtin_amdgcn_s_barrier();
    __builtin_amdgcn_sched_barrier(0);
}
__device__ __forceinline__ void bar_exec() {
    __builtin_amdgcn_s_barrier();
    __builtin_amdgcn_sched_barrier(0);
}

// Poll ctx C stamps >= need (lanes<NM), exec-barrier, then issue the
// next A loads for ctx C into qf (left IN FLIGHT; consumed next phase).
template<int C>
__device__ __forceinline__ void poll_issue(int tid, int G, u32 need,
                                           const u32* slot, const float* Abuf,
                                           int par_next, float2 (&qf)[2]) {
    if (tid < NM) {
        const u32* sp = &slot[(C * NWG + G * NM + tid) * 32];
        while (aload_u32(sp) < need) __builtin_amdgcn_s_sleep(1);
    }
    bar_exec();   // every loader issues only after the poll passed
    const float* Ag = Abuf + C * A_CSZ + par_next * A_PAR + G * (NH * GB);
    qf[0] = aload2(Ag + 4 * tid);
    qf[1] = aload2(Ag + 4 * tid + 2);
}

template<int C>
__device__ __forceinline__ void do_phase(
    int t, int G, int m, int tid, int lane, int wid, int ks,
    const float* __restrict__ x, float* __restrict__ out,
    u32* __restrict__ slot, float* __restrict__ Abuf,
    float* __restrict__ ZPb,
    float2* __restrict__ atile,          // atile[2][ATS]
    float* __restrict__ red,
    const float* __restrict__ wzlds,
    const float (&w)[2][32], const float (&wih)[8],
    float p, float sc,
    float2 (&qw)[2],   // in-flight A(ctx C^1, t)  -> written to atile[C^1]
    float2 (&qf)[2],   // refilled here with A(ctx C, t+1)
    float& h, float& r, float& u, float& htr)
{
    const int par = t & 1;
    const bool own = tid < 64;
    const int ob = tid >> 5;
    const int on = tid & 31;
    const int oi = 32 * m + on;
    const int bglob = G * 4 + C * 2 + ob;

    // x prefetch (cached; long flight time to P5)
    float4 xa = make_float4(0.f, 0.f, 0.f, 0.f), xb = xa;
    if (own) {
        const float4* xp = (const float4*)(x + (bglob * TSTEPS + t) * NI);
        xa = xp[0];
        xb = xp[1];
    }

    // P1: GEMM ctx C from atile[C] (written last phase); butterfly; red
    float a00 = 0.f, a01 = 0.f, a10 = 0.f, a11 = 0.f;
    {
        const float2* at2 = atile + C * ATS + 33 * ks;
        #pragma unroll
        for (int jj = 0; jj < 32; ++jj) {
            float2 a = at2[jj];
            a00 = fmaf(a.x, w[0][jj], a00);
            a01 = fmaf(a.y, w[0][jj], a01);
            a10 = fmaf(a.x, w[1][jj], a10);
            a11 = fmaf(a.y, w[1][jj], a11);
        }
    }
    #pragma unroll
    for (int mm = 16; mm <= 32; mm <<= 1) {
        a00 += __shfl_xor(a00, mm, 64);
        a01 += __shfl_xor(a01, mm, 64);
        a10 += __shfl_xor(a10, mm, 64);
        a11 += __shfl_xor(a11, mm, 64);
    }
    if (lane < 16) {
        float* rp = red + (wid * 16 + lane) * 5;
        rp[0] = a00; rp[1] = a01; rp[2] = a10; rp[3] = a11;
    }

    // P2: z[t-1] finalize load (wave 4; agent load stays in flight)
    const int mr = (C == 0) ? m : (m - 16);
    const bool fin = (wid == 4) && ((C == 0) ? (m < 16) : (m >= 16)) && (t >= 1);
    float zv = 0.f;
    if (fin && lane < NM)
        zv = aload1(ZPb + C * ZP_CSZ + (par ^ 1) * ZP_PAR + G * (GB * NO * NM)
                    + ((mr >> 3) & 1) * (NO * NM) + (mr & 7) * NM + lane);

    bar_lgkm();   // P3: red ready (LDS only; prefetches stay in flight)

    // P4: write the other ctx's in-flight tile (compiler waits qw here)
    {
        float2* dst = atile + (C ^ 1) * ATS;
        const int r0i = 2 * tid;
        dst[r0i + (r0i >> 5)]     = qw[0];
        dst[r0i + 1 + (r0i >> 5)] = qw[1];
    }

    // P5: owners (wave 0) update + publish; wave 0 acks + stamps mid-phase
    if (own) {
        float rec = 0.f;
        #pragma unroll
        for (int wv = 0; wv < 8; ++wv)
            rec += red[(wv * 16 + (on & 15)) * 5 + (on >> 4) * 2 + ob];

        float xv = fmaf(xa.x, wih[0], fmaf(xa.y, wih[1],
                   fmaf(xa.z, wih[2], xa.w * wih[3])));
        xv = fmaf(xb.x, wih[4], fmaf(xb.y, wih[5],
             fmaf(xb.z, wih[6], fmaf(xb.w, wih[7], xv))));

        float drive = 0.5f * (1.0f + htr);
        float rn = r + ((p - r) / 0.2f - 10.0f * r * drive) * 0.001f;
        float un = u + ((p - u) / 1.5f + 10.0f * (1.0f - u) * drive) * 0.001f;
        float hn = h + ((-h + xv + rec) / 0.01f) * 0.001f;
        float htn = tanhf(hn);

        out[OFF_H + (bglob * TSTEPS + t) * NH + oi] = hn;
        out[OFF_R + (bglob * TSTEPS + t) * NH + oi] = rn;
        out[OFF_U + (bglob * TSTEPS + t) * NH + oi] = un;

        astore(&Abuf[C * A_CSZ + ((t + 1) & 1) * A_PAR + G * (NH * GB)
                     + oi * GB + ob], rn * sc * htn);

        // z partial (reduce htn*Whz over the 32 on-lanes; owners = wave 0)
        float zp[NO];
        #pragma unroll
        for (int o = 0; o < NO; ++o) zp[o] = htn * wzlds[on * NO + o];
        #pragma unroll
        for (int d = 1; d <= 16; d <<= 1) {
            #pragma unroll
            for (int o = 0; o < NO; ++o) zp[o] += __shfl_xor(zp[o], d, 64);
        }
        if (on == 0) {   // lanes 0 (ob=0) and 32 (ob=1)
            float* zpp = ZPb + C * ZP_CSZ + par * ZP_PAR + G * (GB * NO * NM)
                         + ob * (NO * NM) + m;
            #pragma unroll
            for (int o = 0; o < NO; ++o) astore(zpp + o * NM, zp[o]);
        }

        h = hn; r = rn; u = un; htr = htn;
    }
    // wave 0: all protocol stores ack'd at the coherence point, then stamp
    if (tid < 64) {
        asm volatile("s_waitcnt vmcnt(0)" ::: "memory");
    }
    if (tid == 0)
        astore_u32(&slot[(C * NWG + G * NM + m) * 32], (u32)(t + 2));

    // z[t-1] finalize reduce + write (wave 4, overlaps wave 0's ack)
    if (fin) {
        zv += __shfl_xor(zv, 1, 64);
        zv += __shfl_xor(zv, 2, 64);
        zv += __shfl_xor(zv, 4, 64);
        zv += __shfl_xor(zv, 8, 64);
        zv += __shfl_xor(zv, 16, 64);
        if (lane == 0) {
            const int bfin = G * 4 + C * 2 + ((mr >> 3) & 1);
            out[OFF_Z + (bfin * TSTEPS + (t - 1)) * NO + (mr & 7)] = zv;
        }
    }

    bar_lgkm();   // P6: atile[C^1] ready for next phase

    // P7+P8: poll own-ctx next stamps (set mid-phase above) and issue
    // next-step loads; they stay in flight through the next phase.
    poll_issue<C>(tid, G, (u32)(t + 2), slot, Abuf, (t + 1) & 1, qf);
}

__global__ __launch_bounds__(BLK, 2) void rnn_stp_kernel(
    const float* __restrict__ x,     // [32][1000][8]
    const float* __restrict__ h0,    // [32][1024]
    const float* __restrict__ r0,    // [32][1024]
    const float* __restrict__ u0,    // [32][1024]
    const float* __restrict__ prel,  // [1024]
    const float* __restrict__ scal,  // [1024]
    const float* __restrict__ Wih,   // [1024][8]
    const float* __restrict__ Whh,   // [1024][1024]
    const float* __restrict__ Wmask, // [1024][1024]
    const float* __restrict__ Whz,   // [8][1024]
    float* __restrict__ out,
    float* __restrict__ ws)
{
    const int tid = threadIdx.x;
    const int g   = blockIdx.x;

    const int G = g & 7;
    const int m = g >> 3;

    u32* slot   = (u32*)ws;
    float* Abuf = ws + WS_A;
    float* ZPb  = ws + WS_ZP;

    const int ib = 32 * m;

    __shared__ float2 atile[2 * ATS];          // per-ctx tiles (pipelined)
    __shared__ float  red[8 * 16 * 5];
    __shared__ float  wzlds[NM * NO];          // [on][o]

    const int lane = tid & 63, wid = tid >> 6;
    const int ks = tid >> 4;
    const int il = tid & 15;

    if (tid < NM * NO)
        wzlds[tid] = Whz[(tid & 7) * NH + ib + (tid >> 3)];

    // Masked weights (fully static indexing -> register-resident, rule #20)
    float w[2][32];
    #pragma unroll
    for (int nn = 0; nn < 2; ++nn) {
        const int row = ib + il + 16 * nn;
        const float* wp = Whh   + row * NH + 32 * ks;
        const float* mp = Wmask + row * NH + 32 * ks;
        #pragma unroll
        for (int jj = 0; jj < 32; ++jj) w[nn][jj] = wp[jj] * mp[jj];
    }

    // ---- owner init (both contexts); wave 0 holds all owner state ----
    const bool own = tid < 64;
    const int ob = tid >> 5;
    const int on = tid & 31;
    const int oi = ib + on;
    float p = 0.f, sc = 0.f;
    float wih[8] = {0.f, 0.f, 0.f, 0.f, 0.f, 0.f, 0.f, 0.f};
    float hA = 0.f, rA = 0.f, uA = 0.f, htA = 0.f;
    float hB = 0.f, rB = 0.f, uB = 0.f, htB = 0.f;
    if (own) {
        p  = prel[oi];
        sc = scal[oi];
        #pragma unroll
        for (int k = 0; k < 8; ++k) wih[k] = Wih[oi * NI + k];
        const int bgA = G * 4 + ob, bgB = G * 4 + 2 + ob;
        hA = h0[bgA * NH + oi]; rA = r0[bgA * NH + oi]; uA = u0[bgA * NH + oi];
        htA = tanhf(hA);
        astore(&Abuf[0 * A_CSZ + G * (NH * GB) + oi * GB + ob], rA * sc * htA);
        hB = h0[bgB * NH + oi]; rB = r0[bgB * NH + oi]; uB = u0[bgB * NH + oi];
        htB = tanhf(hB);
        astore(&Abuf[1 * A_CSZ + G * (NH * GB) + oi * GB + ob], rB * sc * htB);
    }
    // wave 0 drains its init publishes, then stamps both ctxs.
    if (tid < 64) {
        asm volatile("s_waitcnt vmcnt(0)" ::: "memory");
    }
    if (tid == 0) {
        astore_u32(&slot[(0 * NWG + G * NM + m) * 32], 1u);
        astore_u32(&slot[(1 * NWG + G * NM + m) * 32], 1u);
    }

    // ---- prologue: fill atile[0] (blocking) and q1 (left in flight) ----
    float2 q0[2], q1[2];
    poll_issue<0>(tid, G, 1u, slot, Abuf, 0, q0);
    {
        float2* dst = atile;                   // atile[0]
        const int r0i = 2 * tid;
        dst[r0i + (r0i >> 5)]     = q0[0];     // waits q0 (one-time RTT)
        dst[r0i + 1 + (r0i >> 5)] = q0[1];
    }
    poll_issue<1>(tid, G, 1u, slot, Abuf, 0, q1);
    bar_lgkm();   // atile[0] + wzlds ready

    for (int t = 0; t < TSTEPS; ++t) {
        do_phase<0>(t, G, m, tid, lane, wid, ks, x, out, slot, Abuf, ZPb,
                    atile, red, wzlds, w, wih, p, sc,
                    q1, q0, hA, rA, uA, htA);
        do_phase<1>(t, G, m, tid, lane, wid, ks, x, out, slot, Abuf, ZPb,
                    atile, red, wzlds, w, wih, p, sc,
                    q0, q1, hB, rB, uB, htB);
    }

    // ---- epilogue: final P7 polls already confirmed slot >= TSTEPS+1 ----
    __syncthreads();
    if (wid == 4) {
        const int Ce = (m < 16) ? 0 : 1;
        const int mr = (m < 16) ? m : (m - 16);
        float zv = 0.f;
        if (lane < NM)
            zv = aload1(ZPb + Ce * ZP_CSZ + 1 * ZP_PAR + G * (GB * NO * NM)
                        + ((mr >> 3) & 1) * (NO * NM) + (mr & 7) * NM + lane);
        zv += __shfl_xor(zv, 1, 64);
        zv += __shfl_xor(zv, 2, 64);
        zv += __shfl_xor(zv, 4, 64);
        zv += __shfl_xor(zv, 8, 64);
        zv += __shfl_xor(zv, 16, 64);
        if (lane == 0) {
            const int bfin = G * 4 + Ce * 2 + ((mr >> 3) & 1);
            out[OFF_Z + (bfin * TSTEPS + 999) * NO + (mr & 7)] = zv;
        }
    }
}

extern "C" void kernel_launch(void* const* d_in, const int* in_sizes, int n_in,
                              void* d_out, int out_size, void* d_ws, size_t ws_size,
                              hipStream_t stream) {
    const float* x     = (const float*)d_in[0];
    const float* h0    = (const float*)d_in[1];
    const float* r0    = (const float*)d_in[2];
    const float* u0    = (const float*)d_in[3];
    const float* prel  = (const float*)d_in[4];
    const float* scal  = (const float*)d_in[5];
    const float* Wih   = (const float*)d_in[6];
    const float* Whh   = (const float*)d_in[7];
    const float* Wmask = (const float*)d_in[8];
    const float* Whz   = (const float*)d_in[9];
    float* out = (float*)d_out;
    float* ws  = (float*)d_ws;

    // Zero both contexts' stamp slot regions (2 x 256 x 128B).
    hipMemsetAsync(d_ws, 0, NCTX * NWG * 128, stream);

    void* args[] = { &x, &h0, &r0, &u0, &prel, &scal,
                     &Wih, &Whh, &Wmask, &Whz, &out, &ws };
    hipLaunchCooperativeKernel((void*)rnn_stp_kernel, dim3(NWG), dim3(BLK),
                               args, 0, stream);
}

// Round 21
// 3826.657 us; speedup vs baseline: 1.7223x; 1.7223x over previous
//
#include <hip/hip_runtime.h>
#include <math.h>

// RNN with short-term plasticity: persistent cooperative kernel,
// 8 independent groups of 32 WGs (batch-partitioned), per-group barrier.
//
// Round 21: ROUND-11 VERBATIM (best: 3.84 ms; reproduced 3.82 ms as
// round-15's fallback). Rounds 12/13/16/17/18/19/20 exhausted the
// alternatives to this structure's serial chain (distributed polls,
// fused flag+data, co-residency, XCD-L2 sc0 [hang], sparse K-split,
// context interleave, software pipelining) -- all regressed. The
// remaining ~3.8us/step is the cross-CU exchange latency floor:
// publish-ack + stamp RTT + poll-detect + A-stage RTT through L3
// (per-XCD L2s are not coherent), paid 1000x sequentially. VALU 16% /
// HBM 3% confirm latency-bound, not throughput-bound.
//
#define NH 1024
#define NB 32
#define NI 8
#define NO 8
#define TSTEPS 1000

#define NWG 256
#define BLK 512
#define NG 8          // independent groups
#define NM 32         // members (WGs) per group
#define GBATCH 4      // batches per group

// d_out float offsets (z, h, r, u concatenated flat)
#define OFF_Z 0
#define OFF_H (NB * TSTEPS * NO)            // 256000
#define OFF_R (OFF_H + NB * TSTEPS * NH)    // 33024000
#define OFF_U (OFF_R + NB * TSTEPS * NH)    // 65792000

// d_ws float offsets: slots 256x128B = 32 KB, then A, then ZP
#define WS_A  8192                               // A[2][NG][NH][GBATCH]
#define WS_ZP (WS_A + 2 * NG * NH * GBATCH)      // ZP[2][NG][GBATCH][NO][NM]

typedef unsigned long long u64;

__device__ __forceinline__ float2 aload2(const float* p) {
    u64 v = __hip_atomic_load((const u64*)p, __ATOMIC_RELAXED,
                              __HIP_MEMORY_SCOPE_AGENT);
    return __builtin_bit_cast(float2, v);
}
__device__ __forceinline__ float aload1(const float* p) {
    return __hip_atomic_load(p, __ATOMIC_RELAXED, __HIP_MEMORY_SCOPE_AGENT);
}
__device__ __forceinline__ void astore(float* p, float v) {
    __hip_atomic_store(p, v, __ATOMIC_RELAXED, __HIP_MEMORY_SCOPE_AGENT);
}

// Per-group barrier: member m stamps slot [G][m] (128B-strided; round 7:
// packed slots serialize on shared lines); lanes<32 of wave 0 poll the
// group's slots. Release ordering: leading __syncthreads drains vmcnt in
// every wave (agent-scope stores ack'd at the coherence point) first.
__device__ __forceinline__ void groupbar(unsigned* slot, int G, int m,
                                         unsigned stamp) {
    __syncthreads();
    if (threadIdx.x == 0)
        __hip_atomic_store(&slot[(G * NM + m) * 32], stamp,
                           __ATOMIC_RELAXED, __HIP_MEMORY_SCOPE_AGENT);
    if (threadIdx.x < NM) {
        while (__hip_atomic_load(&slot[(G * NM + threadIdx.x) * 32],
                                 __ATOMIC_RELAXED, __HIP_MEMORY_SCOPE_AGENT)
               < stamp)
            __builtin_amdgcn_s_sleep(1);
    }
    __syncthreads();
}

__global__ __launch_bounds__(BLK, 2) void rnn_stp_kernel(
    const float* __restrict__ x,     // [32][1000][8]
    const float* __restrict__ h0,    // [32][1024]
    const float* __restrict__ r0,    // [32][1024]
    const float* __restrict__ u0,    // [32][1024]
    const float* __restrict__ prel,  // [1024]
    const float* __restrict__ scal,  // [1024]
    const float* __restrict__ Wih,   // [1024][8]
    const float* __restrict__ Whh,   // [1024][1024]
    const float* __restrict__ Wmask, // [1024][1024]
    const float* __restrict__ Whz,   // [8][1024]
    float* __restrict__ out,
    float* __restrict__ ws)
{
    const int tid = threadIdx.x;
    const int g   = blockIdx.x;

    // G = g&7 -> group == XCD (locality heuristic only, never correctness).
    const int G = g & 7;
    const int m = g >> 3;

    unsigned* slot = (unsigned*)ws;
    float* Abuf = ws + WS_A;    // [2][NG][NH][GBATCH]
    float* ZP   = ws + WS_ZP;   // [2][NG][GBATCH][NO][NM]

    const int ib = 32 * m;      // first of 32 owned neurons

    // LDS: A-tile padded to 33 float4 per 32 rows (row j -> float4 j + j>>5)
    __shared__ float4 atile[NM * 33];          // 16.9 KB
    __shared__ float  red[8 * 16 * 9];         // 4.6 KB
    __shared__ float  hbuf[GBATCH][NM];        // 512 B

    const int lane = tid & 63, wid = tid >> 6;

    // ---- GEMM roles: ks = tid>>4 (j in [32ks,+32)), il = tid&15 ----
    const int ks = tid >> 4;
    const int il = tid & 15;

    // Masked weights: w[nn][jj] = Weff[32m + il + 16nn][32ks + jj]
    // FULLY static indexing everywhere (rule #20) so these 64 floats stay
    // register-resident.
    float w[2][32];
    #pragma unroll
    for (int nn = 0; nn < 2; ++nn) {
        const int row = 32 * m + il + 16 * nn;
        const float* wp = Whh   + row * NH + 32 * ks;
        const float* mp = Wmask + row * NH + 32 * ks;
        #pragma unroll
        for (int jj = 0; jj < 32; ++jj) w[nn][jj] = wp[jj] * mp[jj];
    }

    // ---- owner role: tid<128: local batch ob = tid>>5, neuron on = tid&31 ----
    const bool own = tid < 128;
    const int ob = tid >> 5;
    const int on = tid & 31;
    const int bglob = G * GBATCH + ob;
    const int oi = ib + on;
    float h = 0.f, r = 0.f, u = 0.f, htr = 0.f, p = 0.f, sc = 0.f;
    float wih[8];
    if (own) {
        h  = h0[bglob * NH + oi];
        r  = r0[bglob * NH + oi];
        u  = u0[bglob * NH + oi];
        p  = prel[oi];
        sc = scal[oi];
        #pragma unroll
        for (int k = 0; k < 8; ++k) wih[k] = Wih[oi * NI + k];
        htr = tanhf(h);
        astore(&Abuf[G * (NH * GBATCH) + oi * GBATCH + ob], r * sc * htr);
    }

    // ---- z-partial consts (waves 0..3): o = lane>>3, nsub = lane&7 ----
    float wzv[4];
    #pragma unroll
    for (int k = 0; k < 4; ++k)
        wzv[k] = Whz[(lane >> 3) * NH + ib + (lane & 7) + 8 * k];
    // ---- z-finalize consts (wave 4, lanes<32): member m -> (bf, of) ----
    const int bf = m >> 3, of = m & 7;

    unsigned stamp = 1;
    groupbar(slot, G, m, stamp); ++stamp;

    for (int t = 0; t < TSTEPS; ++t) {
        const int par = t & 1;

        // ---- stage A[par][G] (16 KB) into LDS; 8 floats (2 rows) each ----
        const float* Ag = Abuf + par * (NG * NH * GBATCH) + G * (NH * GBATCH);
        {
            float2 s0 = aload2(Ag + tid * 8 + 0);
            float2 s1 = aload2(Ag + tid * 8 + 2);
            float2 s2 = aload2(Ag + tid * 8 + 4);
            float2 s3 = aload2(Ag + tid * 8 + 6);
            const int r0i = tid * 2;           // rows r0i, r0i+1
            atile[r0i + (r0i >> 5)]     = make_float4(s0.x, s0.y, s1.x, s1.y);
            atile[r0i + 1 + (r0i >> 5)] = make_float4(s2.x, s2.y, s3.x, s3.y);
        }

        // ---- x prefetch for owners (cached, latency-tolerant) ----
        float4 xa = make_float4(0.f, 0.f, 0.f, 0.f), xb = xa;
        if (own) {
            const float4* xp = (const float4*)(x + (bglob * TSTEPS + t) * NI);
            xa = xp[0];
            xb = xp[1];
        }
        __syncthreads();

        // ---- GEMM: 32 j x 2 rows x 4 b; FULL unroll, static indices ----
        float acc[2][4] = {{0.f,0.f,0.f,0.f},{0.f,0.f,0.f,0.f}};
        {
            const float4* at4 = atile + 33 * ks;
            #pragma unroll
            for (int jj = 0; jj < 32; ++jj) {
                float4 a = at4[jj];
                const float w0 = w[0][jj], w1 = w[1][jj];
                acc[0][0] = fmaf(a.x, w0, acc[0][0]);
                acc[0][1] = fmaf(a.y, w0, acc[0][1]);
                acc[0][2] = fmaf(a.z, w0, acc[0][2]);
                acc[0][3] = fmaf(a.w, w0, acc[0][3]);
                acc[1][0] = fmaf(a.x, w1, acc[1][0]);
                acc[1][1] = fmaf(a.y, w1, acc[1][1]);
                acc[1][2] = fmaf(a.z, w1, acc[1][2]);
                acc[1][3] = fmaf(a.w, w1, acc[1][3]);
            }
        }

        // ---- butterfly over ks low bits (lane bits 4,5) ----
        #pragma unroll
        for (int mm = 16; mm <= 32; mm <<= 1) {
            #pragma unroll
            for (int nn = 0; nn < 2; ++nn) {
                #pragma unroll
                for (int q = 0; q < 4; ++q)
                    acc[nn][q] += __shfl_xor(acc[nn][q], mm, 64);
            }
        }
        if (lane < 16) {
            float* rp = red + (wid * 16 + lane) * 9;
            rp[0] = acc[0][0]; rp[1] = acc[0][1];
            rp[2] = acc[0][2]; rp[3] = acc[0][3];
            rp[4] = acc[1][0]; rp[5] = acc[1][1];
            rp[6] = acc[1][2]; rp[7] = acc[1][3];
        }
        __syncthreads();

        // ---- owner: combine 8 wave partials, update state, write out ----
        if (own) {
            float rec = 0.f;
            #pragma unroll
            for (int wv = 0; wv < 8; ++wv)
                rec += red[(wv * 16 + (on & 15)) * 9 + (on >> 4) * 4 + ob];

            float xv = fmaf(xa.x, wih[0], fmaf(xa.y, wih[1],
                       fmaf(xa.z, wih[2], xa.w * wih[3])));
            xv = fmaf(xb.x, wih[4], fmaf(xb.y, wih[5],
                 fmaf(xb.z, wih[6], fmaf(xb.w, wih[7], xv))));

            float drive = 0.5f * (1.0f + htr);
            float rn = r + ((p - r) / 0.2f - 10.0f * r * drive) * 0.001f;
            float un = u + ((p - u) / 1.5f + 10.0f * (1.0f - u) * drive) * 0.001f;
            float hn = h + ((-h + xv + rec) / 0.01f) * 0.001f;
            float htn = tanhf(hn);

            out[OFF_H + (bglob * TSTEPS + t) * NH + oi] = hn;
            out[OFF_R + (bglob * TSTEPS + t) * NH + oi] = rn;
            out[OFF_U + (bglob * TSTEPS + t) * NH + oi] = un;

            astore(&Abuf[(par ^ 1) * (NG * NH * GBATCH) + G * (NH * GBATCH)
                         + oi * GBATCH + ob], rn * sc * htn);
            hbuf[ob][on] = htn;

            h = hn; r = rn; u = un; htr = htn;
        }
        __syncthreads();   // hbuf visible to z-partial waves

        // ---- z partials for step t: waves 0..3 (b = wid) ----
        if (wid < 4) {
            const int o = lane >> 3, ns = lane & 7;
            float zp = 0.f;
            #pragma unroll
            for (int k = 0; k < 4; ++k)
                zp = fmaf(hbuf[wid][ns + 8 * k], wzv[k], zp);
            zp += __shfl_xor(zp, 1, 64);
            zp += __shfl_xor(zp, 2, 64);
            zp += __shfl_xor(zp, 4, 64);
            if (ns == 0)
                astore(&ZP[par * (NG * GBATCH * NO * NM)
                           + G * (GBATCH * NO * NM)
                           + wid * (NO * NM) + o * NM + m], zp);
        }
        // ---- z finalize for step t-1: wave 4, lanes<32 ----
        if (t >= 1 && wid == 4 && lane < NM) {
            float v = aload1(ZP + (par ^ 1) * (NG * GBATCH * NO * NM)
                             + G * (GBATCH * NO * NM)
                             + bf * (NO * NM) + of * NM + lane);
            v += __shfl_xor(v, 1, 64);
            v += __shfl_xor(v, 2, 64);
            v += __shfl_xor(v, 4, 64);
            v += __shfl_xor(v, 8, 64);
            v += __shfl_xor(v, 16, 64);
            if (lane == 0)
                out[OFF_Z + ((G * GBATCH + bf) * TSTEPS + (t - 1)) * NO + of] = v;
        }

        groupbar(slot, G, m, stamp); ++stamp;
    }

    // ---- epilogue: finalize z[999] (partials in ZP[1]) ----
    if (wid == 4 && lane < NM) {
        float v = aload1(ZP + 1 * (NG * GBATCH * NO * NM)
                         + G * (GBATCH * NO * NM)
                         + bf * (NO * NM) + of * NM + lane);
        v += __shfl_xor(v, 1, 64);
        v += __shfl_xor(v, 2, 64);
        v += __shfl_xor(v, 4, 64);
        v += __shfl_xor(v, 8, 64);
        v += __shfl_xor(v, 16, 64);
        if (lane == 0)
            out[OFF_Z + ((G * GBATCH + bf) * TSTEPS + 999) * NO + of] = v;
    }
}

extern "C" void kernel_launch(void* const* d_in, const int* in_sizes, int n_in,
                              void* d_out, int out_size, void* d_ws, size_t ws_size,
                              hipStream_t stream) {
    const float* x     = (const float*)d_in[0];
    const float* h0    = (const float*)d_in[1];
    const float* r0    = (const float*)d_in[2];
    const float* u0    = (const float*)d_in[3];
    const float* prel  = (const float*)d_in[4];
    const float* scal  = (const float*)d_in[5];
    const float* Wih   = (const float*)d_in[6];
    const float* Whh   = (const float*)d_in[7];
    const float* Wmask = (const float*)d_in[8];
    const float* Whz   = (const float*)d_in[9];
    float* out = (float*)d_out;
    float* ws  = (float*)d_ws;

    // Zero the 256 barrier slots (128B apart) each launch.
    hipMemsetAsync(d_ws, 0, NWG * 128, stream);

    void* args[] = { &x, &h0, &r0, &u0, &prel, &scal,
                     &Wih, &Whh, &Wmask, &Whz, &out, &ws };
    hipLaunchCooperativeKernel((void*)rnn_stp_kernel, dim3(NWG), dim3(BLK),
                               args, 0, stream);
}